// Round 1
// baseline (673.159 us; speedup 1.0000x reference)
//
#include <hip/hip_runtime.h>

#define TOK 1003
#define NST 21
#define NORM2 0.360673760222241f  // (1/sqrt(16)) * log2(e)  -> use exp2 softmax (exact)

// =====================================================================
// GEMM core: out(M x 128) = X(M x 128) @ W(128 x 128)
// Tile 128x128, k-tiles of 64, micro-tile 8x8, 256 threads.
// WHDK: W stored as (H=8, D=128, K=16)  [proj weights]; else row-major (128,128).
// =====================================================================
template <bool WHDK>
__device__ __forceinline__ void gemm_core(const float* __restrict__ X,
                                          const float* __restrict__ W,
                                          float* __restrict__ out, int m0) {
  __shared__ __align__(16) float Xs[64][128];   // Xs[dd][r]  (X transposed)
  __shared__ __align__(16) float Ws[64][132];   // Ws[dd][c]  (+4 pad)
  const int tid = threadIdx.x;
  const int tx = tid & 15, ty = tid >> 4;

  float acc[8][8];
#pragma unroll
  for (int i = 0; i < 8; ++i)
#pragma unroll
    for (int j = 0; j < 8; ++j) acc[i][j] = 0.f;

  for (int dt = 0; dt < 2; ++dt) {
    const int d0 = dt * 64;
    __syncthreads();
    // stage X^T: Xs[dd][r] = X[(m0+r)*128 + d0+dd]
#pragma unroll
    for (int it = 0; it < 8; ++it) {
      int idx = tid + it * 256;           // 0..2047
      int r = idx & 127, dc = idx >> 7;   // dc 0..15
      float4 v = *(const float4*)(X + (size_t)(m0 + r) * 128 + d0 + dc * 4);
      Xs[dc * 4 + 0][r] = v.x;
      Xs[dc * 4 + 1][r] = v.y;
      Xs[dc * 4 + 2][r] = v.z;
      Xs[dc * 4 + 3][r] = v.w;
    }
    // stage W: Ws[dd][c]
#pragma unroll
    for (int it = 0; it < 8; ++it) {
      int idx = tid + it * 256;           // 0..2047
      int dd = idx >> 5, q4 = idx & 31;
      int c = q4 * 4;
      float4 v;
      if (WHDK) {
        int hh = q4 >> 2, k0 = (q4 & 3) * 4;
        v = *(const float4*)(W + hh * 2048 + (d0 + dd) * 16 + k0);
      } else {
        v = *(const float4*)(W + (size_t)(d0 + dd) * 128 + c);
      }
      *(float4*)&Ws[dd][c] = v;
    }
    __syncthreads();
#pragma unroll 8
    for (int dd = 0; dd < 64; ++dd) {
      float a[8], bc[8];
#pragma unroll
      for (int i = 0; i < 8; ++i) a[i] = Xs[dd][ty * 8 + i];
#pragma unroll
      for (int j = 0; j < 8; ++j) bc[j] = Ws[dd][tx * 8 + j];
#pragma unroll
      for (int i = 0; i < 8; ++i)
#pragma unroll
        for (int j = 0; j < 8; ++j) acc[i][j] = fmaf(a[i], bc[j], acc[i][j]);
    }
  }
#pragma unroll
  for (int i = 0; i < 8; ++i) {
    float* o = out + (size_t)(m0 + ty * 8 + i) * 128 + tx * 8;
    *(float4*)o = make_float4(acc[i][0], acc[i][1], acc[i][2], acc[i][3]);
    *(float4*)(o + 4) = make_float4(acc[i][4], acc[i][5], acc[i][6], acc[i][7]);
  }
}

// 4 big projections: grid (256 M-tiles, 4 projs)
__global__ __launch_bounds__(256, 1) void proj_big(
    const float* __restrict__ q, const float* __restrict__ hx,
    const float* __restrict__ Wtt, const float* __restrict__ Wts,
    const float* __restrict__ Wkc, const float* __restrict__ Wvc,
    float* __restrict__ ws) {
  int py = blockIdx.y;
  const float* X = (py < 2) ? q : hx;
  const float* W = (py == 0) ? Wtt : (py == 1) ? Wts : (py == 2) ? Wkc : Wvc;
  float* out = ws + (size_t)py * 4194304;
  gemm_core<true>(X, W, out, blockIdx.x * 128);
}

// Output projection: heads(32768x128) @ Wout(128x128) -> d_out
__global__ __launch_bounds__(256, 1) void out_proj(
    const float* __restrict__ heads, const float* __restrict__ Wout,
    float* __restrict__ out) {
  gemm_core<false>(heads, Wout, out, blockIdx.x * 128);
}

// =====================================================================
// Station projections: Q_st, K_s, V_s  (only 21 rows per batch)
// grid 672 blocks = (b,s), 128 threads = output column (h*16+k)
// =====================================================================
__global__ __launch_bounds__(128, 1) void proj_st(
    const float* __restrict__ q, const float* __restrict__ hx,
    const float* __restrict__ Wq, const float* __restrict__ Wk,
    const float* __restrict__ Wv, float* __restrict__ Qst,
    float* __restrict__ Ks, float* __restrict__ Vs) {
  int bs = blockIdx.x;  // 0..671
  int b = bs / 21, s = bs - b * 21;
  __shared__ float xq[128], xh[128];
  int tid = threadIdx.x;
  xq[tid] = q[(size_t)(b * 1024 + s) * 128 + tid];
  xh[tid] = hx[(size_t)(b * 1024 + s) * 128 + tid];
  __syncthreads();
  int hh = tid >> 4, k = tid & 15;
#pragma unroll
  for (int p = 0; p < 3; ++p) {
    const float* xr = (p == 0) ? xq : xh;
    const float* W = ((p == 0) ? Wq : (p == 1) ? Wk : Wv) + hh * 2048 + k;
    float sacc = 0.f;
#pragma unroll 8
    for (int d = 0; d < 128; ++d) sacc = fmaf(xr[d], W[d * 16], sacc);
    float* O = (p == 0) ? Qst : (p == 1) ? Ks : Vs;
    O[(size_t)(b * 21 + s) * 128 + tid] = sacc;
  }
}

// =====================================================================
// Attention. grid 512 = (h,b) x half. 128 threads, 4 query-slots each.
// Slot u in [0,1024): u<1003 -> token t=u (n=21+u, query Q_tt / Q_ts),
//                     u>=1003 -> station s=u-1003 (n=s, query Q_st).
// Phase 1: softmax over 1003 token keys (K_c/V_c).
// Phase 2: token slots only: softmax over 21 station keys (K_s/V_s), added.
// Fixed-shift softmax: p = 2^(s - 24), s = NORM2 * (q . k); exact result.
// =====================================================================
__global__ __launch_bounds__(128, 1) void attn(
    const float* __restrict__ Qtt, const float* __restrict__ Qts,
    const float* __restrict__ Kc, const float* __restrict__ Vc,
    const float* __restrict__ Qst, const float* __restrict__ Ks,
    const float* __restrict__ Vs, float* __restrict__ heads) {
  const int bx = blockIdx.x;
  const int hb = bx >> 1, half = bx & 1;
  const int hh = hb >> 5, b = hb & 31;
  const int tid = threadIdx.x;
  __shared__ __align__(16) float Kl[128][16];
  __shared__ __align__(16) float Vl[128][16];

  int u[4];
  float q1[4][16], acc[4][16], l[4];
#pragma unroll
  for (int jq = 0; jq < 4; ++jq) {
    u[jq] = half * 512 + tid * 4 + jq;
    const float* src =
        (u[jq] < TOK) ? (Qtt + (size_t)(b * 1024 + 21 + u[jq]) * 128 + hh * 16)
                      : (Qst + (size_t)(b * 21 + (u[jq] - TOK)) * 128 + hh * 16);
#pragma unroll
    for (int c = 0; c < 4; ++c) {
      float4 v = *(const float4*)(src + c * 4);
      q1[jq][c * 4 + 0] = v.x * NORM2;
      q1[jq][c * 4 + 1] = v.y * NORM2;
      q1[jq][c * 4 + 2] = v.z * NORM2;
      q1[jq][c * 4 + 3] = v.w * NORM2;
    }
    l[jq] = 0.f;
#pragma unroll
    for (int k = 0; k < 16; ++k) acc[jq][k] = 0.f;
  }

  // ---- phase 1: token keys ----
  for (int kt = 0; kt < 8; ++kt) {
    int j0 = kt * 128;
    int cnt = min(128, TOK - j0);
    __syncthreads();
    for (int i = tid; i < cnt * 4; i += 128) {
      int j = i >> 2, c = i & 3;
      size_t off = (size_t)(b * 1024 + 21 + j0 + j) * 128 + hh * 16 + c * 4;
      *(float4*)&Kl[j][c * 4] = *(const float4*)(Kc + off);
      *(float4*)&Vl[j][c * 4] = *(const float4*)(Vc + off);
    }
    __syncthreads();
    for (int j = 0; j < cnt; ++j) {
      float kr[16], vr[16];
#pragma unroll
      for (int c = 0; c < 4; ++c) {
        float4 kv = *(const float4*)&Kl[j][c * 4];
        kr[c * 4 + 0] = kv.x; kr[c * 4 + 1] = kv.y;
        kr[c * 4 + 2] = kv.z; kr[c * 4 + 3] = kv.w;
        float4 vv = *(const float4*)&Vl[j][c * 4];
        vr[c * 4 + 0] = vv.x; vr[c * 4 + 1] = vv.y;
        vr[c * 4 + 2] = vv.z; vr[c * 4 + 3] = vv.w;
      }
#pragma unroll
      for (int jq = 0; jq < 4; ++jq) {
        float s = 0.f;
#pragma unroll
        for (int k = 0; k < 16; ++k) s = fmaf(q1[jq][k], kr[k], s);
        float p = exp2f(s - 24.f);
        l[jq] += p;
#pragma unroll
        for (int k = 0; k < 16; ++k) acc[jq][k] = fmaf(p, vr[k], acc[jq][k]);
      }
    }
  }
  // write phase-1 result
#pragma unroll
  for (int jq = 0; jq < 4; ++jq) {
    int n = (u[jq] < TOK) ? 21 + u[jq] : u[jq] - TOK;
    float inv = 1.f / l[jq];
    float* o = heads + (size_t)(b * 1024 + n) * 128 + hh * 16;
#pragma unroll
    for (int c = 0; c < 4; ++c)
      *(float4*)(o + c * 4) =
          make_float4(acc[jq][c * 4 + 0] * inv, acc[jq][c * 4 + 1] * inv,
                      acc[jq][c * 4 + 2] * inv, acc[jq][c * 4 + 3] * inv);
  }

  // ---- phase 2: station keys (token slots only) ----
  __syncthreads();
  for (int i = tid; i < NST * 4; i += 128) {
    int j = i >> 2, c = i & 3;
    size_t off = (size_t)(b * 21 + j) * 128 + hh * 16 + c * 4;
    *(float4*)&Kl[j][c * 4] = *(const float4*)(Ks + off);
    *(float4*)&Vl[j][c * 4] = *(const float4*)(Vs + off);
  }
#pragma unroll
  for (int jq = 0; jq < 4; ++jq) {
    int urow = (u[jq] < TOK) ? u[jq] : 0;  // dummy (unused) row for stations
    const float* src = Qts + (size_t)(b * 1024 + 21 + urow) * 128 + hh * 16;
#pragma unroll
    for (int c = 0; c < 4; ++c) {
      float4 v = *(const float4*)(src + c * 4);
      q1[jq][c * 4 + 0] = v.x * NORM2;
      q1[jq][c * 4 + 1] = v.y * NORM2;
      q1[jq][c * 4 + 2] = v.z * NORM2;
      q1[jq][c * 4 + 3] = v.w * NORM2;
    }
    l[jq] = 0.f;
#pragma unroll
    for (int k = 0; k < 16; ++k) acc[jq][k] = 0.f;
  }
  __syncthreads();
  for (int j = 0; j < NST; ++j) {
    float kr[16], vr[16];
#pragma unroll
    for (int c = 0; c < 4; ++c) {
      float4 kv = *(const float4*)&Kl[j][c * 4];
      kr[c * 4 + 0] = kv.x; kr[c * 4 + 1] = kv.y;
      kr[c * 4 + 2] = kv.z; kr[c * 4 + 3] = kv.w;
      float4 vv = *(const float4*)&Vl[j][c * 4];
      vr[c * 4 + 0] = vv.x; vr[c * 4 + 1] = vv.y;
      vr[c * 4 + 2] = vv.z; vr[c * 4 + 3] = vv.w;
    }
#pragma unroll
    for (int jq = 0; jq < 4; ++jq) {
      float s = 0.f;
#pragma unroll
      for (int k = 0; k < 16; ++k) s = fmaf(q1[jq][k], kr[k], s);
      float p = exp2f(s - 24.f);
      l[jq] += p;
#pragma unroll
      for (int k = 0; k < 16; ++k) acc[jq][k] = fmaf(p, vr[k], acc[jq][k]);
    }
  }
#pragma unroll
  for (int jq = 0; jq < 4; ++jq) {
    if (u[jq] < TOK) {
      float inv = 1.f / l[jq];
      float* o = heads + (size_t)(b * 1024 + 21 + u[jq]) * 128 + hh * 16;
#pragma unroll
      for (int c = 0; c < 4; ++c) {
        float4 prev = *(float4*)(o + c * 4);
        prev.x = fmaf(acc[jq][c * 4 + 0], inv, prev.x);
        prev.y = fmaf(acc[jq][c * 4 + 1], inv, prev.y);
        prev.z = fmaf(acc[jq][c * 4 + 2], inv, prev.z);
        prev.w = fmaf(acc[jq][c * 4 + 3], inv, prev.w);
        *(float4*)(o + c * 4) = prev;
      }
    }
  }
}

extern "C" void kernel_launch(void* const* d_in, const int* in_sizes, int n_in,
                              void* d_out, int out_size, void* d_ws,
                              size_t ws_size, hipStream_t stream) {
  (void)in_sizes; (void)n_in; (void)out_size; (void)ws_size;
  const float* q     = (const float*)d_in[0];
  const float* hx    = (const float*)d_in[1];
  const float* W_qts = (const float*)d_in[2];  // W_query_custom   -> Q_ts
  const float* W_qtt = (const float*)d_in[3];  // W_query_custom_1 -> Q_tt
  const float* W_kc  = (const float*)d_in[4];  // W_key_custom     -> K_c
  const float* W_vc  = (const float*)d_in[5];  // W_val_custom     -> V_c
  const float* W_qst = (const float*)d_in[6];  // W_query_charge_1 -> Q_st
  const float* W_ks  = (const float*)d_in[7];  // W_key_charge     -> K_s
  const float* W_vs  = (const float*)d_in[8];  // W_val_charge     -> V_s
  const float* W_out = (const float*)d_in[9];

  float* ws    = (float*)d_ws;
  float* Qtt   = ws;                       // (b,n,h*16+k)  4.19M floats
  float* Qts   = ws + 1 * 4194304;
  float* Kc    = ws + 2 * 4194304;
  float* Vc    = ws + 3 * 4194304;
  float* heads = ws + 4 * 4194304;         // (b,n,h*16+k)
  float* Qst   = ws + 5 * 4194304;         // (b,s,h*16+k)  86016 floats
  float* Ks    = Qst + 86016;
  float* Vs    = Ks + 86016;

  hipLaunchKernelGGL(proj_big, dim3(256, 4), dim3(256), 0, stream, q, hx,
                     W_qtt, W_qts, W_kc, W_vc, ws);
  hipLaunchKernelGGL(proj_st, dim3(672), dim3(128), 0, stream, q, hx, W_qst,
                     W_ks, W_vs, Qst, Ks, Vs);
  hipLaunchKernelGGL(attn, dim3(512), dim3(128), 0, stream, Qtt, Qts, Kc, Vc,
                     Qst, Ks, Vs, heads);
  hipLaunchKernelGGL(out_proj, dim3(256), dim3(256), 0, stream, heads, W_out,
                     (float*)d_out);
}

// Round 3
// 230.814 us; speedup vs baseline: 2.9165x; 2.9165x over previous
//
#include <hip/hip_runtime.h>

typedef __bf16 bf16x8 __attribute__((ext_vector_type(8)));
typedef float f32x4 __attribute__((ext_vector_type(4)));
typedef float f32x16 __attribute__((ext_vector_type(16)));
typedef unsigned int uint32;
typedef unsigned short ushort16;

#define TOK 1003
#define NST 21
#define SCL 0.3606737602222409f  // 0.25 * log2(e): folded into Q; softmax = exp2(s-24)

union U4B { uint4 u; bf16x8 b; };

__device__ __forceinline__ uint32 pkbf(float a, float b) {
  uint32 ua = __float_as_uint(a), ub = __float_as_uint(b);
  ua += 0x7fffu + ((ua >> 16) & 1u);
  ub += 0x7fffu + ((ub >> 16) & 1u);
  return (ua >> 16) | (ub & 0xffff0000u);
}
__device__ __forceinline__ ushort16 bf1(float a) {
  uint32 u = __float_as_uint(a);
  u += 0x7fffu + ((u >> 16) & 1u);
  return (ushort16)(u >> 16);
}

// =====================================================================
// wt_prep: transpose + bf16-cast the 5 weight matrices.
// bid 0..3: proj weights (8,128,16): Wt[c][d] = W[h(c)][d][k(c)], c=h*16+k
// bid 4   : W_out (128,128):         Wt[e][c] = W[c][e]
// =====================================================================
__global__ __launch_bounds__(256) void wt_prep(
    const float* __restrict__ W0, const float* __restrict__ W1,
    const float* __restrict__ W2, const float* __restrict__ W3,
    const float* __restrict__ W4, ushort16* __restrict__ WtAll) {
  int bid = blockIdx.x;
  const float* W = (bid == 0) ? W0 : (bid == 1) ? W1 : (bid == 2) ? W2
                   : (bid == 3) ? W3 : W4;
  ushort16* dst = WtAll + bid * 16384;
  int tid = threadIdx.x;
  for (int it = 0; it < 64; ++it) {
    int i = it * 256 + tid;        // 0..16383
    int inner = i & 127, outer = i >> 7;
    float v;
    if (bid < 4) {
      // outer = c, inner = d
      int h = outer >> 4, k = outer & 15;
      v = W[h * 2048 + inner * 16 + k];
    } else {
      // outer = e, inner = c
      v = W[inner * 128 + outer];
    }
    dst[outer * 128 + inner] = bf1(v);
  }
}

// =====================================================================
// MFMA GEMM body: out(rows x128) = X(rows x 128) @ Wmat(128x128)
//   A = X rows (f32 -> bf16, optional scale), B from pre-transposed Wt.
//   64 rows per block (4 waves x 16-row M-tile). K=128 in 4 chunks of 32.
// mode 0: Qmain bf16 [h][b][n][16], scaled   mode 1: Qts same
// mode 2: Kc bf16 [h][b][j<1003][16] (skip n<21)  mode 3: Vc same
// mode 4: f32 out [m][128]
// =====================================================================
__device__ __forceinline__ void mm_body(const float* __restrict__ X,
                                        const ushort16* __restrict__ WtG,
                                        int m0, int mode, void* outp) {
  __shared__ ushort16 Wl[128 * 136];
  int tid = threadIdx.x;
  for (int r = 0; r < 8; ++r) {
    int i = r * 256 + tid;          // 0..2047 uint4 transfers (8 ushorts each)
    int e = i >> 4, j = i & 15;     // row 0..127, col-group 0..15  (FIXED)
    *(uint4*)&Wl[e * 136 + j * 8] = *(const uint4*)(WtG + e * 128 + j * 8);
  }
  __syncthreads();
  int wave = tid >> 6, lane = tid & 63;
  int quad = lane >> 4, l15 = lane & 15;
  int mrow = m0 + wave * 16 + l15;  // A-row for this lane
  float scale = (mode <= 1) ? SCL : 1.0f;

  f32x4 c[8];
#pragma unroll
  for (int nt = 0; nt < 8; ++nt)
#pragma unroll
    for (int r = 0; r < 4; ++r) c[nt][r] = 0.f;

#pragma unroll
  for (int dk = 0; dk < 4; ++dk) {
    const float* xs = X + (size_t)mrow * 128 + dk * 32 + quad * 8;
    float4 xa = *(const float4*)xs;
    float4 xb = *(const float4*)(xs + 4);
    U4B af;
    af.u.x = pkbf(xa.x * scale, xa.y * scale);
    af.u.y = pkbf(xa.z * scale, xa.w * scale);
    af.u.z = pkbf(xb.x * scale, xb.y * scale);
    af.u.w = pkbf(xb.z * scale, xb.w * scale);
#pragma unroll
    for (int nt = 0; nt < 8; ++nt) {
      U4B bg;
      bg.u = *(const uint4*)&Wl[(nt * 16 + l15) * 136 + dk * 32 + quad * 8];
      c[nt] = __builtin_amdgcn_mfma_f32_16x16x32_bf16(af.b, bg.b, c[nt], 0, 0, 0);
    }
  }
  // epilogue: C row = quad*4+r, col = nt*16 + l15
#pragma unroll
  for (int nt = 0; nt < 8; ++nt) {
#pragma unroll
    for (int r = 0; r < 4; ++r) {
      int g = m0 + wave * 16 + quad * 4 + r;  // global row
      float v = c[nt][r];
      if (mode == 4) {
        ((float*)outp)[(size_t)g * 128 + nt * 16 + l15] = v;
      } else {
        int b = g >> 10, n = g & 1023;
        if (mode >= 2) {
          if (n < NST) continue;
          ((ushort16*)outp)[(((size_t)nt * 32 + b) * 1024 + (n - NST)) * 16 + l15] = bf1(v);
        } else {
          ((ushort16*)outp)[(((size_t)nt * 32 + b) * 1024 + n) * 16 + l15] = bf1(v);
        }
      }
    }
  }
}

__global__ __launch_bounds__(256) void proj4(
    const float* __restrict__ q, const float* __restrict__ hx,
    const ushort16* __restrict__ WtAll, ushort16* __restrict__ Qm,
    ushort16* __restrict__ Qts, ushort16* __restrict__ Kc,
    ushort16* __restrict__ Vc) {
  int mode = blockIdx.x >> 9, mb = blockIdx.x & 511;
  const float* X = (mode < 2) ? q : hx;
  void* outp = (mode == 0) ? (void*)Qm : (mode == 1) ? (void*)Qts
               : (mode == 2) ? (void*)Kc : (void*)Vc;
  mm_body(X, WtAll + mode * 16384, mb * 64, mode, outp);
}

__global__ __launch_bounds__(256) void outproj(
    const float* __restrict__ heads, const ushort16* __restrict__ WtAll,
    float* __restrict__ out) {
  mm_body(heads, WtAll + 4 * 16384, blockIdx.x * 64, 4, out);
}

// =====================================================================
// Station projections (f32 compute, tiny): Q_st -> Qmain rows 0..20 (bf16,
// scaled), K_s/V_s -> f32 buffers [h][b][21][16].
// =====================================================================
__global__ __launch_bounds__(128) void proj_st(
    const float* __restrict__ q, const float* __restrict__ hx,
    const float* __restrict__ Wq, const float* __restrict__ Wk,
    const float* __restrict__ Wv, ushort16* __restrict__ Qm,
    float* __restrict__ Ks, float* __restrict__ Vs) {
  int bs = blockIdx.x;  // 0..671
  int b = bs / 21, s = bs - b * 21;
  __shared__ float xq[128], xh[128];
  int tid = threadIdx.x;
  xq[tid] = q[(size_t)(b * 1024 + s) * 128 + tid];
  xh[tid] = hx[(size_t)(b * 1024 + s) * 128 + tid];
  __syncthreads();
  int hh = tid >> 4, k = tid & 15;
#pragma unroll
  for (int p = 0; p < 3; ++p) {
    const float* xr = (p == 0) ? xq : xh;
    const float* W = ((p == 0) ? Wq : (p == 1) ? Wk : Wv) + hh * 2048 + k;
    float sacc = 0.f;
#pragma unroll 8
    for (int d = 0; d < 128; ++d) sacc = fmaf(xr[d], W[d * 16], sacc);
    if (p == 0) {
      Qm[(((size_t)hh * 32 + b) * 1024 + s) * 16 + k] = bf1(sacc * SCL);
    } else {
      float* O = (p == 1) ? Ks : Vs;
      O[(((size_t)hh * 32 + b) * 21 + s) * 16 + k] = sacc;
    }
  }
}

// =====================================================================
// Main attention (MFMA): queries n 0..1023 (stations use Q_st rows, tokens
// Q_tt rows -- both already merged in Qmain) over 1003 token keys.
// grid 1024 = (h,b) x 4 q-chunks; 256 thr = 4 waves x 64 queries.
// S^T tile = K(32x16) x Q^T(16x32) via mfma_32x32x16; fixed-shift exp2;
// P -> bf16 -> per-wave LDS -> PV via mfma_16x16x32.
// =====================================================================
__global__ __launch_bounds__(256) void attn_main(
    const ushort16* __restrict__ Qm, const ushort16* __restrict__ Kc,
    const ushort16* __restrict__ Vc, float* __restrict__ heads) {
  int bx = blockIdx.x;
  int hb = bx & 255, qc = bx >> 8;
  int h = hb >> 5, b = hb & 31;
  int tid = threadIdx.x;
  int wave = tid >> 6, lane = tid & 63;
  int l5 = lane >> 5, l31 = lane & 31;
  int quad = lane >> 4, l15 = lane & 15;

  __shared__ ushort16 Kl[128 * 24];    // [key][24] (16 used, 48B rows)
  __shared__ ushort16 Vl[16 * 136];    // transposed [d][136]
  __shared__ ushort16 Pt[4][64 * 40];  // per wave [q][40] (32 used)
  __shared__ float lbuf[4][64];

  const ushort16* Qbase = Qm + ((size_t)(h * 32 + b)) * 16384;
  const ushort16* Kbase = Kc + ((size_t)(h * 32 + b)) * 16384;
  const ushort16* Vbase = Vc + ((size_t)(h * 32 + b)) * 16384;

  int qw0 = qc * 256 + wave * 64;
  U4B qf[2];
#pragma unroll
  for (int f = 0; f < 2; ++f) {
    int qq = qw0 + f * 32 + l31;
    qf[f].u = *(const uint4*)(Qbase + qq * 16 + l5 * 8);
  }
  f32x4 o[4];
#pragma unroll
  for (int mt = 0; mt < 4; ++mt)
#pragma unroll
    for (int r = 0; r < 4; ++r) o[mt][r] = 0.f;
  float lsum[2] = {0.f, 0.f};

  for (int kb = 0; kb < 8; ++kb) {
    int j0 = kb * 128;
    __syncthreads();
    {  // stage K rows + V transposed
      int key = tid >> 1, half = tid & 1;
      int j = j0 + key;
      uint4 kv = make_uint4(0, 0, 0, 0), vv = make_uint4(0, 0, 0, 0);
      if (j < TOK) {
        kv = *(const uint4*)(Kbase + j * 16 + half * 8);
        vv = *(const uint4*)(Vbase + j * 16 + half * 8);
      }
      *(uint4*)&Kl[key * 24 + half * 8] = kv;
      ushort16 tmp[8];
      *(uint4*)tmp = vv;
#pragma unroll
      for (int d2 = 0; d2 < 8; ++d2) Vl[(half * 8 + d2) * 136 + key] = tmp[d2];
    }
    __syncthreads();
#pragma unroll 1
    for (int kt = 0; kt < 4; ++kt) {
      int key0 = kt * 32;
      U4B af;
      af.u = *(const uint4*)&Kl[(key0 + l31) * 24 + l5 * 8];
      f32x16 cz;
#pragma unroll
      for (int i = 0; i < 16; ++i) cz[i] = 0.f;
      f32x16 c0 = __builtin_amdgcn_mfma_f32_32x32x16_bf16(af.b, qf[0].b, cz, 0, 0, 0);
      f32x16 c1 = __builtin_amdgcn_mfma_f32_32x32x16_bf16(af.b, qf[1].b, cz, 0, 0, 0);
#pragma unroll
      for (int f = 0; f < 2; ++f) {
        const f32x16& c = f ? c1 : c0;
        int qq = f * 32 + l31;
#pragma unroll
        for (int g = 0; g < 4; ++g) {
          float p0 = __builtin_amdgcn_exp2f(c[4 * g + 0] - 24.f);
          float p1 = __builtin_amdgcn_exp2f(c[4 * g + 1] - 24.f);
          float p2 = __builtin_amdgcn_exp2f(c[4 * g + 2] - 24.f);
          float p3 = __builtin_amdgcn_exp2f(c[4 * g + 3] - 24.f);
          lsum[f] += (p0 + p1) + (p2 + p3);
          uint2 w2 = make_uint2(pkbf(p0, p1), pkbf(p2, p3));
          // C row = (reg&3) + 8*(reg>>2) + 4*l5 -> keys in groups of 4
          *(uint2*)&Pt[wave][qq * 40 + 4 * l5 + 8 * g] = w2;
        }
      }
      U4B vf;
      vf.u = *(const uint4*)&Vl[l15 * 136 + key0 + quad * 8];
#pragma unroll
      for (int mt = 0; mt < 4; ++mt) {
        U4B pf;
        pf.u = *(const uint4*)&Pt[wave][(mt * 16 + l15) * 40 + quad * 8];
        o[mt] = __builtin_amdgcn_mfma_f32_16x16x32_bf16(pf.b, vf.b, o[mt], 0, 0, 0);
      }
    }
  }
#pragma unroll
  for (int f = 0; f < 2; ++f) {
    float lt = lsum[f] + __shfl_xor(lsum[f], 32, 64);
    lbuf[wave][f * 32 + l31] = lt;
  }
#pragma unroll
  for (int mt = 0; mt < 4; ++mt) {
#pragma unroll
    for (int r = 0; r < 4; ++r) {
      int qrow = mt * 16 + quad * 4 + r;
      float inv = 1.f / lbuf[wave][qrow];
      int n = qw0 + qrow;
      heads[((size_t)b * 1024 + n) * 128 + h * 16 + l15] = o[mt][r] * inv;
    }
  }
}

// =====================================================================
// Token-over-station attention (f32 VALU, tiny): heads[token] += A_ts @ V_s
// grid 1024 = (h,b) x 4 chunks; 1 token query per thread.
// =====================================================================
__global__ __launch_bounds__(256) void attn_st(
    const ushort16* __restrict__ Qts, const float* __restrict__ Ks,
    const float* __restrict__ Vs, float* __restrict__ heads) {
  int bx = blockIdx.x;
  int hb = bx & 255, qc = bx >> 8;
  int h = hb >> 5, b = hb & 31;
  __shared__ float Kl2[NST * 16], Vl2[NST * 16];
  int tid = threadIdx.x;
  for (int i = tid; i < NST * 16; i += 256) {
    Kl2[i] = Ks[(size_t)(h * 32 + b) * (NST * 16) + i];
    Vl2[i] = Vs[(size_t)(h * 32 + b) * (NST * 16) + i];
  }
  __syncthreads();
  int t = qc * 256 + tid;
  if (t >= TOK) return;
  const ushort16* qp = Qts + (((size_t)(h * 32 + b)) * 1024 + NST + t) * 16;
  float qv[16];
  uint4 a = *(const uint4*)qp;
  uint4 b2 = *(const uint4*)(qp + 8);
  uint32 aw[8];
  *(uint4*)aw = a;
  *(uint4*)(aw + 4) = b2;
#pragma unroll
  for (int i = 0; i < 8; ++i) {
    qv[2 * i] = __uint_as_float(aw[i] << 16);
    qv[2 * i + 1] = __uint_as_float(aw[i] & 0xffff0000u);
  }
  float acc[16], l = 0.f;
#pragma unroll
  for (int k = 0; k < 16; ++k) acc[k] = 0.f;
  for (int s = 0; s < NST; ++s) {
    float sc = 0.f;
#pragma unroll
    for (int k = 0; k < 16; ++k) sc = fmaf(qv[k], Kl2[s * 16 + k], sc);
    float p = __builtin_amdgcn_exp2f(sc - 24.f);
    l += p;
#pragma unroll
    for (int k = 0; k < 16; ++k) acc[k] = fmaf(p, Vl2[s * 16 + k], acc[k]);
  }
  float inv = 1.f / l;
  float* hp = heads + ((size_t)b * 1024 + NST + t) * 128 + h * 16;
#pragma unroll
  for (int k = 0; k < 16; ++k) hp[k] += acc[k] * inv;
}

// =====================================================================
extern "C" void kernel_launch(void* const* d_in, const int* in_sizes, int n_in,
                              void* d_out, int out_size, void* d_ws,
                              size_t ws_size, hipStream_t stream) {
  (void)in_sizes; (void)n_in; (void)out_size; (void)ws_size;
  const float* q     = (const float*)d_in[0];
  const float* hx    = (const float*)d_in[1];
  const float* W_qts = (const float*)d_in[2];  // W_query_custom   -> Q_ts
  const float* W_qtt = (const float*)d_in[3];  // W_query_custom_1 -> Q_tt
  const float* W_kc  = (const float*)d_in[4];
  const float* W_vc  = (const float*)d_in[5];
  const float* W_qst = (const float*)d_in[6];  // W_query_charge_1 -> Q_st
  const float* W_ks  = (const float*)d_in[7];
  const float* W_vs  = (const float*)d_in[8];
  const float* W_out = (const float*)d_in[9];

  char* ws = (char*)d_ws;
  ushort16* Qm    = (ushort16*)(ws + 0);           // 8 MB  [h][b][1024][16]
  ushort16* Qts   = (ushort16*)(ws + 8388608);     // 8 MB
  ushort16* Kc    = (ushort16*)(ws + 16777216);    // 8 MB  [h][b][j][16]
  ushort16* Vc    = (ushort16*)(ws + 25165824);    // 8 MB
  float*    heads = (float*)   (ws + 33554432);    // 16 MB [b][n][128]
  float*    Ks    = (float*)   (ws + 50331648);    // 344 KB
  float*    Vs    = (float*)   (ws + 50675712);    // 344 KB
  ushort16* WtAll = (ushort16*)(ws + 51019776);    // 160 KB (5 x 128x128 bf16)

  hipLaunchKernelGGL(wt_prep, dim3(5), dim3(256), 0, stream,
                     W_qtt, W_qts, W_kc, W_vc, W_out, WtAll);
  hipLaunchKernelGGL(proj4, dim3(2048), dim3(256), 0, stream,
                     q, hx, WtAll, Qm, Qts, Kc, Vc);
  hipLaunchKernelGGL(proj_st, dim3(672), dim3(128), 0, stream,
                     q, hx, W_qst, W_ks, W_vs, Qm, Ks, Vs);
  hipLaunchKernelGGL(attn_main, dim3(1024), dim3(256), 0, stream,
                     Qm, Kc, Vc, heads);
  hipLaunchKernelGGL(attn_st, dim3(1024), dim3(256), 0, stream,
                     Qts, Ks, Vs, heads);
  hipLaunchKernelGGL(outproj, dim3(512), dim3(256), 0, stream,
                     heads, WtAll, (float*)d_out);
}

// Round 5
// 201.773 us; speedup vs baseline: 3.3362x; 1.1439x over previous
//
#include <hip/hip_runtime.h>

typedef __bf16 bf16x8 __attribute__((ext_vector_type(8)));
typedef float f32x4 __attribute__((ext_vector_type(4)));
typedef float f32x16 __attribute__((ext_vector_type(16)));
typedef unsigned int uint32;
typedef unsigned short u16;

#define NST 21
#define TOK 1003
#define SCL 0.3606737602222409f  // 0.25*log2(e); softmax = exp2(s-24), fixed shift

union U4B { uint4 u; bf16x8 b; };

__device__ __forceinline__ uint32 pkbf(float a, float b) {  // RTNE pack
  uint32 ua = __float_as_uint(a), ub = __float_as_uint(b);
  ua += 0x7fffu + ((ua >> 16) & 1u);
  ub += 0x7fffu + ((ub >> 16) & 1u);
  return (ua >> 16) | (ub & 0xffff0000u);
}
__device__ __forceinline__ u16 bf1(float a) {
  uint32 u = __float_as_uint(a);
  u += 0x7fffu + ((u >> 16) & 1u);
  return (u16)(u >> 16);
}
__device__ __forceinline__ float ubf(u16 u) {
  return __uint_as_float(((uint32)u) << 16);
}
// 1-instr truncating pack: lo16 = lo.hi16, hi16 = hi.hi16 (CK idiom)
__device__ __forceinline__ uint32 pkperm(float lo, float hi) {
  return __builtin_amdgcn_perm(__float_as_uint(hi), __float_as_uint(lo), 0x07060302u);
}

// =====================================================================
// prep: (a) 5 weight transposes -> bf16 WtAll, (b) q/hx f32->bf16 cast,
// (c) station projections Q_st->Qm rows<21, K_s/V_s (+zero pad rows 21..31)
// grid 4613 = 5 wt + 4096 cast + 512 station (2 stations/block)
// =====================================================================
__global__ __launch_bounds__(256) void prep(
    const float* __restrict__ q, const float* __restrict__ hx,
    const float* __restrict__ W0, const float* __restrict__ W1,
    const float* __restrict__ W2, const float* __restrict__ W3,
    const float* __restrict__ W4, const float* __restrict__ Wqst,
    const float* __restrict__ Wks, const float* __restrict__ Wvs,
    u16* __restrict__ qhbf, u16* __restrict__ WtAll, u16* __restrict__ Qm,
    u16* __restrict__ Ks, u16* __restrict__ Vs) {
  int bid = blockIdx.x, tid = threadIdx.x;
  __shared__ float xq2[2][128], xh2[2][128];
  if (bid < 5) {
    const float* W = (bid == 0) ? W0 : (bid == 1) ? W1 : (bid == 2) ? W2
                     : (bid == 3) ? W3 : W4;
    u16* dst = WtAll + bid * 16384;
    for (int it = 0; it < 64; ++it) {
      int i = it * 256 + tid;
      int inner = i & 127, outer = i >> 7;
      float v;
      if (bid < 4) {
        int h = outer >> 4, k = outer & 15;
        v = W[h * 2048 + inner * 16 + k];
      } else {
        v = W[inner * 128 + outer];
      }
      dst[outer * 128 + inner] = bf1(v);
    }
  } else if (bid < 4101) {
    int i0 = (bid - 5) * 2048 + tid * 8;  // 8 floats per thread
    const float* src = (i0 < 4194304) ? (q + i0) : (hx + (i0 - 4194304));
    float4 a = *(const float4*)src;
    float4 b = *(const float4*)(src + 4);
    uint4 o;
    o.x = pkbf(a.x, a.y); o.y = pkbf(a.z, a.w);
    o.z = pkbf(b.x, b.y); o.w = pkbf(b.z, b.w);
    *((uint4*)qhbf + (i0 >> 3)) = o;
  } else {
    int t2 = bid - 4101;            // 0..511
    int sub = tid >> 7, col = tid & 127;
    int hh = col >> 4, k = col & 15;
    int bs2 = t2 * 2 + sub;         // 0..1023
    int b2 = bs2 >> 5, s = bs2 & 31;
    if (s < NST) {
      xq2[sub][col] = q[(size_t)(b2 * 1024 + s) * 128 + col];
      xh2[sub][col] = hx[(size_t)(b2 * 1024 + s) * 128 + col];
    }
    __syncthreads();
    if (s < NST) {
      const float* Wq = Wqst + hh * 2048 + k;
      const float* Wk = Wks + hh * 2048 + k;
      const float* Wv = Wvs + hh * 2048 + k;
      float dq = 0.f, dk_ = 0.f, dv = 0.f;
#pragma unroll 8
      for (int d = 0; d < 128; ++d) {
        float xq = xq2[sub][d], xh = xh2[sub][d];
        dq = fmaf(xq, Wq[d * 16], dq);
        dk_ = fmaf(xh, Wk[d * 16], dk_);
        dv = fmaf(xh, Wv[d * 16], dv);
      }
      Qm[(((size_t)hh * 32 + b2) * 1024 + s) * 16 + k] = bf1(dq * SCL);
      Ks[(((size_t)hh * 32 + b2) * 32 + s) * 16 + k] = bf1(dk_);
      Vs[(((size_t)hh * 32 + b2) * 16 + k) * 32 + s] = bf1(dv);
    } else {
      Ks[(((size_t)hh * 32 + b2) * 32 + s) * 16 + k] = 0;
      Vs[(((size_t)hh * 32 + b2) * 16 + k) * 32 + s] = 0;
    }
  }
}

// =====================================================================
// MFMA GEMM body: out(64 rows x 128) = A_bf16(64x128) @ Wt^T; A pre-cast.
// mode 0: Qm bf16 [h][b][n][16] scaled, skip n<21 (prep owns those rows)
// mode 1: Qts bf16, scaled, all rows       mode 2: Kc bf16 [h][b][n][16]
// mode 3: Vc bf16 TRANSPOSED [h][b][k16][n1024]   mode 4: f32 out [m][128]
// =====================================================================
__device__ __forceinline__ void mm_body(const u16* __restrict__ A,
                                        const u16* __restrict__ WtG,
                                        int m0, int mode, void* outp) {
  __shared__ u16 Wl[128 * 136];
  int tid = threadIdx.x;
#pragma unroll
  for (int r = 0; r < 8; ++r) {
    int i = r * 256 + tid;
    int e = i >> 4, j = i & 15;
    *(uint4*)&Wl[e * 136 + j * 8] = *(const uint4*)(WtG + e * 128 + j * 8);
  }
  __syncthreads();
  int wave = tid >> 6, lane = tid & 63;
  int quad = lane >> 4, l15 = lane & 15;
  int mrow = m0 + wave * 16 + l15;

  f32x4 c[8];
#pragma unroll
  for (int nt = 0; nt < 8; ++nt)
#pragma unroll
    for (int r = 0; r < 4; ++r) c[nt][r] = 0.f;

#pragma unroll
  for (int dk = 0; dk < 4; ++dk) {
    U4B af;
    af.u = *(const uint4*)(A + (size_t)mrow * 128 + dk * 32 + quad * 8);
#pragma unroll
    for (int nt = 0; nt < 8; ++nt) {
      U4B bg;
      bg.u = *(const uint4*)&Wl[(nt * 16 + l15) * 136 + dk * 32 + quad * 8];
      c[nt] = __builtin_amdgcn_mfma_f32_16x16x32_bf16(af.b, bg.b, c[nt], 0, 0, 0);
    }
  }
  int gbase = m0 + wave * 16 + quad * 4;
  int bb = gbase >> 10, n0 = gbase & 1023;
  if (mode == 4) {
#pragma unroll
    for (int nt = 0; nt < 8; ++nt)
#pragma unroll
      for (int r = 0; r < 4; ++r)
        ((float*)outp)[(size_t)(gbase + r) * 128 + nt * 16 + l15] = c[nt][r];
  } else if (mode == 3) {
#pragma unroll
    for (int nt = 0; nt < 8; ++nt) {
      uint2 w2 = make_uint2(pkbf(c[nt][0], c[nt][1]), pkbf(c[nt][2], c[nt][3]));
      *(uint2*)((u16*)outp + (((size_t)nt * 32 + bb) * 16 + l15) * 1024 + n0) = w2;
    }
  } else {
    float scale = (mode <= 1) ? SCL : 1.0f;
#pragma unroll
    for (int nt = 0; nt < 8; ++nt)
#pragma unroll
      for (int r = 0; r < 4; ++r) {
        int n = n0 + r;
        if (mode == 0 && n < NST) continue;
        ((u16*)outp)[(((size_t)nt * 32 + bb) * 1024 + n) * 16 + l15] =
            bf1(c[nt][r] * scale);
      }
  }
}

__global__ __launch_bounds__(256) void proj4(
    const u16* __restrict__ qbf, const u16* __restrict__ hbf,
    const u16* __restrict__ WtAll, u16* __restrict__ Qm,
    u16* __restrict__ Qts, u16* __restrict__ Kc, u16* __restrict__ Vc) {
  int mode = blockIdx.x >> 9, mb = blockIdx.x & 511;
  const u16* A = (mode < 2) ? qbf : hbf;
  void* outp = (mode == 0) ? (void*)Qm : (mode == 1) ? (void*)Qts
               : (mode == 2) ? (void*)Kc : (void*)Vc;
  mm_body(A, WtAll + mode * 16384, mb * 64, mode, outp);
}

__global__ __launch_bounds__(256) void outproj(
    const u16* __restrict__ heads, const u16* __restrict__ WtAll,
    float* __restrict__ out) {
  mm_body(heads, WtAll + 4 * 16384, blockIdx.x * 64, 4, out);
}

// =====================================================================
// attn_main (round-3-proven skeleton + in-line VALU optimizations):
// per (h,b,qc): 256 q rows over 1024 key slots (keys<21 masked at kb0/kt0).
// S^T via mfma_32x32x16; exp2 fixed shift; P packed with v_perm (truncate);
// PV + row-sum both via mfma_16x16x32 (ones-B). No station pass here.
// =====================================================================
__global__ __launch_bounds__(256) void attn_main(
    const u16* __restrict__ Qm, const u16* __restrict__ Kc,
    const u16* __restrict__ Vc, u16* __restrict__ heads) {
  int bx = blockIdx.x;
  int hb = bx & 255, qc = bx >> 8;
  int h = hb >> 5, b = hb & 31;
  int tid = threadIdx.x;
  int wave = tid >> 6, lane = tid & 63;
  int l5 = lane >> 5, l31 = lane & 31;
  int quad = lane >> 4, l15 = lane & 15;

  __shared__ u16 Kl[128 * 24];     // [key][24] (16 used)
  __shared__ u16 Vl[16 * 136];     // [k][136] (keys along row)
  __shared__ u16 Pt[4][64 * 40];   // per wave [q][40] (32 used)

  const u16* Qbase = Qm + ((size_t)(h * 32 + b)) * 16384;
  const u16* Kbase = Kc + ((size_t)(h * 32 + b)) * 16384;
  const u16* Vbase = Vc + ((size_t)(h * 32 + b)) * 16384;

  int qw0 = qc * 256 + wave * 64;
  U4B qf0, qf1;
  qf0.u = *(const uint4*)(Qbase + (size_t)(qw0 + l31) * 16 + l5 * 8);
  qf1.u = *(const uint4*)(Qbase + (size_t)(qw0 + 32 + l31) * 16 + l5 * 8);

  f32x16 zero16;
#pragma unroll
  for (int i = 0; i < 16; ++i) zero16[i] = 0.f;
  U4B ones;
  ones.u = make_uint4(0x3F803F80u, 0x3F803F80u, 0x3F803F80u, 0x3F803F80u);

  f32x4 o[4], la[4];
#pragma unroll
  for (int mt = 0; mt < 4; ++mt)
#pragma unroll
    for (int r = 0; r < 4; ++r) { o[mt][r] = 0.f; la[mt][r] = 0.f; }

#pragma unroll 1
  for (int kb = 0; kb < 8; ++kb) {
    int j0 = kb * 128;
    __syncthreads();
    {
      int key = tid >> 1, half = tid & 1;
      *(uint4*)&Kl[key * 24 + half * 8] =
          *(const uint4*)(Kbase + (size_t)(j0 + key) * 16 + half * 8);
      int d = tid >> 4, kg = tid & 15;
      *(uint4*)&Vl[d * 136 + kg * 8] =
          *(const uint4*)(Vbase + (size_t)d * 1024 + j0 + kg * 8);
    }
    __syncthreads();
#pragma unroll 1
    for (int kt = 0; kt < 4; ++kt) {
      int key0 = kt * 32;
      U4B af;
      af.u = *(const uint4*)&Kl[(key0 + l31) * 24 + l5 * 8];
      f32x16 c0 =
          __builtin_amdgcn_mfma_f32_32x32x16_bf16(af.b, qf0.b, zero16, 0, 0, 0);
      f32x16 c1 =
          __builtin_amdgcn_mfma_f32_32x32x16_bf16(af.b, qf1.b, zero16, 0, 0, 0);
      bool masked = (kb == 0) && (kt == 0);
#pragma unroll
      for (int f = 0; f < 2; ++f) {
        const f32x16& c = f ? c1 : c0;
        int qq = f * 32 + l31;
#pragma unroll
        for (int g = 0; g < 4; ++g) {
          float p0 = __builtin_amdgcn_exp2f(c[4 * g + 0] - 24.f);
          float p1 = __builtin_amdgcn_exp2f(c[4 * g + 1] - 24.f);
          float p2 = __builtin_amdgcn_exp2f(c[4 * g + 2] - 24.f);
          float p3 = __builtin_amdgcn_exp2f(c[4 * g + 3] - 24.f);
          if (masked) {  // key index of value r is r + 8*g + 4*l5; zero keys<21
            int kb0 = 8 * g + 4 * l5;
            p0 = (kb0 + 0 < NST) ? 0.f : p0;
            p1 = (kb0 + 1 < NST) ? 0.f : p1;
            p2 = (kb0 + 2 < NST) ? 0.f : p2;
            p3 = (kb0 + 3 < NST) ? 0.f : p3;
          }
          uint2 w2 = make_uint2(pkperm(p0, p1), pkperm(p2, p3));
          *(uint2*)&Pt[wave][qq * 40 + 4 * l5 + 8 * g] = w2;
        }
      }
      U4B vf;
      vf.u = *(const uint4*)&Vl[l15 * 136 + key0 + quad * 8];
#pragma unroll
      for (int mt = 0; mt < 4; ++mt) {
        U4B pf;
        pf.u = *(const uint4*)&Pt[wave][(mt * 16 + l15) * 40 + quad * 8];
        o[mt] = __builtin_amdgcn_mfma_f32_16x16x32_bf16(pf.b, vf.b, o[mt], 0, 0, 0);
        la[mt] =
            __builtin_amdgcn_mfma_f32_16x16x32_bf16(pf.b, ones.b, la[mt], 0, 0, 0);
      }
    }
  }

  // epilogue: heads bf16 (la C-layout matches o C-layout row-for-row)
#pragma unroll
  for (int mt = 0; mt < 4; ++mt)
#pragma unroll
    for (int r = 0; r < 4; ++r) {
      int n = qw0 + mt * 16 + quad * 4 + r;
      float val = o[mt][r] * __builtin_amdgcn_rcpf(la[mt][r]);
      heads[((size_t)b * 1024 + n) * 128 + h * 16 + l15] = bf1(val);
    }
}

// =====================================================================
// attn_st: token-over-station attention (tiny), bf16 RMW add into heads.
// grid 1024 = (h,b) x 4 chunks; 1 token query per thread.
// =====================================================================
__global__ __launch_bounds__(256) void attn_st(
    const u16* __restrict__ Qts, const u16* __restrict__ Ks,
    const u16* __restrict__ Vs, u16* __restrict__ heads) {
  int bx = blockIdx.x;
  int hb = bx & 255, qc = bx >> 8;
  int h = hb >> 5, b = hb & 31;
  __shared__ float Kl2[NST * 16], Vl2[NST * 16];
  int tid = threadIdx.x;
  const u16* KsB = Ks + (size_t)(h * 32 + b) * 512;
  const u16* VsB = Vs + (size_t)(h * 32 + b) * 512;
  for (int i = tid; i < NST * 16; i += 256) {
    int s = i >> 4, k = i & 15;
    Kl2[i] = ubf(KsB[s * 16 + k]);
    Vl2[i] = ubf(VsB[k * 32 + s]);
  }
  __syncthreads();
  int t = qc * 256 + tid;
  if (t >= TOK) return;
  const u16* qp = Qts + (((size_t)(h * 32 + b)) * 1024 + NST + t) * 16;
  uint4 a = *(const uint4*)qp;
  uint4 b2 = *(const uint4*)(qp + 8);
  uint32 aw[8];
  *(uint4*)aw = a;
  *(uint4*)(aw + 4) = b2;
  float qv[16];
#pragma unroll
  for (int i = 0; i < 8; ++i) {
    qv[2 * i] = __uint_as_float(aw[i] << 16);
    qv[2 * i + 1] = __uint_as_float(aw[i] & 0xffff0000u);
  }
  float acc[16], l = 0.f;
#pragma unroll
  for (int k = 0; k < 16; ++k) acc[k] = 0.f;
#pragma unroll 1
  for (int s = 0; s < NST; ++s) {
    float sc = 0.f;
#pragma unroll
    for (int k = 0; k < 16; ++k) sc = fmaf(qv[k], Kl2[s * 16 + k], sc);
    float p = __builtin_amdgcn_exp2f(sc - 24.f);
    l += p;
#pragma unroll
    for (int k = 0; k < 16; ++k) acc[k] = fmaf(p, Vl2[s * 16 + k], acc[k]);
  }
  float inv = 1.f / l;
  u16* hp = heads + ((size_t)b * 1024 + NST + t) * 128 + h * 16;
#pragma unroll
  for (int k = 0; k < 16; ++k) hp[k] = bf1(ubf(hp[k]) + acc[k] * inv);
}

// =====================================================================
extern "C" void kernel_launch(void* const* d_in, const int* in_sizes, int n_in,
                              void* d_out, int out_size, void* d_ws,
                              size_t ws_size, hipStream_t stream) {
  (void)in_sizes; (void)n_in; (void)out_size; (void)ws_size;
  const float* q     = (const float*)d_in[0];
  const float* hx    = (const float*)d_in[1];
  const float* W_qts = (const float*)d_in[2];  // W_query_custom   -> Q_ts
  const float* W_qtt = (const float*)d_in[3];  // W_query_custom_1 -> Q_tt
  const float* W_kc  = (const float*)d_in[4];
  const float* W_vc  = (const float*)d_in[5];
  const float* W_qst = (const float*)d_in[6];  // W_query_charge_1 -> Q_st
  const float* W_ks  = (const float*)d_in[7];
  const float* W_vs  = (const float*)d_in[8];
  const float* W_out = (const float*)d_in[9];

  char* ws = (char*)d_ws;
  u16* qhbf  = (u16*)(ws + 0);          // q:8MB + hx:8MB (bf16 casts)
  u16* heads = (u16*)(ws + 0);          // reuse qbf slot (dead after proj4)
  u16* hbf   = (u16*)(ws + 8388608);
  u16* Qm    = (u16*)(ws + 16777216);   // [h][b][1024][16]
  u16* Qts   = (u16*)(ws + 25165824);
  u16* Kc    = (u16*)(ws + 33554432);   // [h][b][1024][16]
  u16* Vc    = (u16*)(ws + 41943040);   // [h][b][16][1024] (transposed)
  u16* Ks    = (u16*)(ws + 50331648);   // [h][b][32][16]
  u16* Vs    = (u16*)(ws + 50593792);   // [h][b][16][32]
  u16* WtAll = (u16*)(ws + 50855936);   // 5 x 128x128 bf16

  hipLaunchKernelGGL(prep, dim3(4613), dim3(256), 0, stream,
                     q, hx, W_qtt, W_qts, W_kc, W_vc, W_out, W_qst, W_ks, W_vs,
                     qhbf, WtAll, Qm, Ks, Vs);
  hipLaunchKernelGGL(proj4, dim3(2048), dim3(256), 0, stream,
                     qhbf, hbf, WtAll, Qm, Qts, Kc, Vc);
  hipLaunchKernelGGL(attn_main, dim3(1024), dim3(256), 0, stream,
                     Qm, Kc, Vc, heads);
  hipLaunchKernelGGL(attn_st, dim3(1024), dim3(256), 0, stream,
                     Qts, Ks, Vs, heads);
  hipLaunchKernelGGL(outproj, dim3(512), dim3(256), 0, stream,
                     heads, WtAll, (float*)d_out);
}

// Round 6
// 190.100 us; speedup vs baseline: 3.5411x; 1.0614x over previous
//
#include <hip/hip_runtime.h>

typedef __bf16 bf16x8 __attribute__((ext_vector_type(8)));
typedef float f32x4 __attribute__((ext_vector_type(4)));
typedef float f32x16 __attribute__((ext_vector_type(16)));
typedef unsigned int uint32;
typedef unsigned short u16;

#define NST 21
#define TOK 1003
#define SCL 0.3606737602222409f  // 0.25*log2(e); softmax = exp2(s), shift-free

union U4B { uint4 u; bf16x8 b; };

__device__ __forceinline__ uint32 pkbf(float a, float b) {  // RTNE pack
  uint32 ua = __float_as_uint(a), ub = __float_as_uint(b);
  ua += 0x7fffu + ((ua >> 16) & 1u);
  ub += 0x7fffu + ((ub >> 16) & 1u);
  return (ua >> 16) | (ub & 0xffff0000u);
}
__device__ __forceinline__ u16 bf1(float a) {
  uint32 u = __float_as_uint(a);
  u += 0x7fffu + ((u >> 16) & 1u);
  return (u16)(u >> 16);
}
// 1-instr truncating pack: lo16 = lo.hi16, hi16 = hi.hi16 (CK idiom)
__device__ __forceinline__ uint32 pkperm(float lo, float hi) {
  return __builtin_amdgcn_perm(__float_as_uint(hi), __float_as_uint(lo), 0x07060302u);
}

// =====================================================================
// prep: (a) 5 weight transposes -> bf16 WtAll (40 blocks, 8 per matrix),
// (b) q/hx f32->bf16 cast, (c) station projections Q_st->Qm rows<21,
// K_s/V_s (+zero pad rows 21..31). grid 4648 = 40 + 4096 + 512
// =====================================================================
__global__ __launch_bounds__(256) void prep(
    const float* __restrict__ q, const float* __restrict__ hx,
    const float* __restrict__ W0, const float* __restrict__ W1,
    const float* __restrict__ W2, const float* __restrict__ W3,
    const float* __restrict__ W4, const float* __restrict__ Wqst,
    const float* __restrict__ Wks, const float* __restrict__ Wvs,
    u16* __restrict__ qhbf, u16* __restrict__ WtAll, u16* __restrict__ Qm,
    u16* __restrict__ Ks, u16* __restrict__ Vs) {
  int bid = blockIdx.x, tid = threadIdx.x;
  __shared__ float xq2[2][128], xh2[2][128];
  if (bid < 40) {
    int w = bid >> 3, seg = bid & 7;
    const float* W = (w == 0) ? W0 : (w == 1) ? W1 : (w == 2) ? W2
                     : (w == 3) ? W3 : W4;
    u16* dst = WtAll + w * 16384;
#pragma unroll
    for (int it = 0; it < 8; ++it) {
      int i = seg * 2048 + it * 256 + tid;  // 0..16383
      int inner = i & 127, outer = i >> 7;
      float v;
      if (w < 4) {
        int h = outer >> 4, k = outer & 15;
        v = W[h * 2048 + inner * 16 + k];
      } else {
        v = W[inner * 128 + outer];
      }
      dst[outer * 128 + inner] = bf1(v);
    }
  } else if (bid < 4136) {
    int i0 = (bid - 40) * 2048 + tid * 8;  // 8 floats per thread
    const float* src = (i0 < 4194304) ? (q + i0) : (hx + (i0 - 4194304));
    float4 a = *(const float4*)src;
    float4 b = *(const float4*)(src + 4);
    uint4 o;
    o.x = pkbf(a.x, a.y); o.y = pkbf(a.z, a.w);
    o.z = pkbf(b.x, b.y); o.w = pkbf(b.z, b.w);
    *((uint4*)qhbf + (i0 >> 3)) = o;
  } else {
    int t2 = bid - 4136;            // 0..511
    int sub = tid >> 7, col = tid & 127;
    int hh = col >> 4, k = col & 15;
    int bs2 = t2 * 2 + sub;         // 0..1023
    int b2 = bs2 >> 5, s = bs2 & 31;
    if (s < NST) {
      xq2[sub][col] = q[(size_t)(b2 * 1024 + s) * 128 + col];
      xh2[sub][col] = hx[(size_t)(b2 * 1024 + s) * 128 + col];
    }
    __syncthreads();
    if (s < NST) {
      const float* Wq = Wqst + hh * 2048 + k;
      const float* Wk = Wks + hh * 2048 + k;
      const float* Wv = Wvs + hh * 2048 + k;
      float dq = 0.f, dk_ = 0.f, dv = 0.f;
#pragma unroll 8
      for (int d = 0; d < 128; ++d) {
        float xq = xq2[sub][d], xh = xh2[sub][d];
        dq = fmaf(xq, Wq[d * 16], dq);
        dk_ = fmaf(xh, Wk[d * 16], dk_);
        dv = fmaf(xh, Wv[d * 16], dv);
      }
      Qm[(((size_t)hh * 32 + b2) * 1024 + s) * 16 + k] = bf1(dq * SCL);
      Ks[(((size_t)hh * 32 + b2) * 32 + s) * 16 + k] = bf1(dk_);
      Vs[(((size_t)hh * 32 + b2) * 16 + k) * 32 + s] = bf1(dv);
    } else {
      Ks[(((size_t)hh * 32 + b2) * 32 + s) * 16 + k] = 0;
      Vs[(((size_t)hh * 32 + b2) * 16 + k) * 32 + s] = 0;
    }
  }
}

// =====================================================================
// MFMA GEMM body: out(64 rows x 128) = A_bf16(64x128) @ Wt^T; A pre-cast.
// mode 0: Qm bf16 [h][b][n][16] scaled, skip n<21 (prep owns those rows)
// mode 1: Qts bf16, scaled, all rows       mode 2: Kc bf16 [h][b][n][16]
// mode 3: Vc bf16 TRANSPOSED [h][b][k16][n1024]   mode 4: f32 out [m][128]
// =====================================================================
__device__ __forceinline__ void mm_body(const u16* __restrict__ A,
                                        const u16* __restrict__ WtG,
                                        int m0, int mode, void* outp) {
  __shared__ u16 Wl[128 * 136];
  int tid = threadIdx.x;
#pragma unroll
  for (int r = 0; r < 8; ++r) {
    int i = r * 256 + tid;
    int e = i >> 4, j = i & 15;
    *(uint4*)&Wl[e * 136 + j * 8] = *(const uint4*)(WtG + e * 128 + j * 8);
  }
  __syncthreads();
  int wave = tid >> 6, lane = tid & 63;
  int quad = lane >> 4, l15 = lane & 15;
  int mrow = m0 + wave * 16 + l15;

  f32x4 c[8];
#pragma unroll
  for (int nt = 0; nt < 8; ++nt)
#pragma unroll
    for (int r = 0; r < 4; ++r) c[nt][r] = 0.f;

#pragma unroll
  for (int dk = 0; dk < 4; ++dk) {
    U4B af;
    af.u = *(const uint4*)(A + (size_t)mrow * 128 + dk * 32 + quad * 8);
#pragma unroll
    for (int nt = 0; nt < 8; ++nt) {
      U4B bg;
      bg.u = *(const uint4*)&Wl[(nt * 16 + l15) * 136 + dk * 32 + quad * 8];
      c[nt] = __builtin_amdgcn_mfma_f32_16x16x32_bf16(af.b, bg.b, c[nt], 0, 0, 0);
    }
  }
  int gbase = m0 + wave * 16 + quad * 4;
  int bb = gbase >> 10, n0 = gbase & 1023;
  if (mode == 4) {
#pragma unroll
    for (int nt = 0; nt < 8; ++nt)
#pragma unroll
      for (int r = 0; r < 4; ++r)
        ((float*)outp)[(size_t)(gbase + r) * 128 + nt * 16 + l15] = c[nt][r];
  } else if (mode == 3) {
#pragma unroll
    for (int nt = 0; nt < 8; ++nt) {
      uint2 w2 = make_uint2(pkbf(c[nt][0], c[nt][1]), pkbf(c[nt][2], c[nt][3]));
      *(uint2*)((u16*)outp + (((size_t)nt * 32 + bb) * 16 + l15) * 1024 + n0) = w2;
    }
  } else {
    float scale = (mode <= 1) ? SCL : 1.0f;
#pragma unroll
    for (int nt = 0; nt < 8; ++nt)
#pragma unroll
      for (int r = 0; r < 4; ++r) {
        int n = n0 + r;
        if (mode == 0 && n < NST) continue;
        ((u16*)outp)[(((size_t)nt * 32 + bb) * 1024 + n) * 16 + l15] =
            bf1(c[nt][r] * scale);
      }
  }
}

__global__ __launch_bounds__(256) void proj4(
    const u16* __restrict__ qbf, const u16* __restrict__ hbf,
    const u16* __restrict__ WtAll, u16* __restrict__ Qm,
    u16* __restrict__ Qts, u16* __restrict__ Kc, u16* __restrict__ Vc) {
  int mode = blockIdx.x >> 9, mb = blockIdx.x & 511;
  const u16* A = (mode < 2) ? qbf : hbf;
  void* outp = (mode == 0) ? (void*)Qm : (mode == 1) ? (void*)Qts
               : (mode == 2) ? (void*)Kc : (void*)Vc;
  mm_body(A, WtAll + mode * 16384, mb * 64, mode, outp);
}

__global__ __launch_bounds__(256) void outproj(
    const u16* __restrict__ heads, const u16* __restrict__ WtAll,
    float* __restrict__ out) {
  mm_body(heads, WtAll + 4 * 16384, blockIdx.x * 64, 4, out);
}

// =====================================================================
// attn_main (r5 skeleton, fused station pass, conflict-free LDS strides):
// per (h,b,qc): 256 q rows over 1024 key slots (keys<21 masked at kb0/kt0),
// then one masked station kt-step (keys>=21 masked) from KsL/VsL.
// S^T via mfma_32x32x16; exp2 shift-free; P packed with v_perm;
// PV + row-sum via mfma_16x16x32 (ones-B). Straight-line, unroll 1.
// =====================================================================
__global__ __launch_bounds__(256) void attn_main(
    const u16* __restrict__ Qm, const u16* __restrict__ Qts,
    const u16* __restrict__ Kc, const u16* __restrict__ Vc,
    const u16* __restrict__ Ks, const u16* __restrict__ Vs,
    u16* __restrict__ heads) {
  int bx = blockIdx.x;
  int hb = bx & 255, qc = bx >> 8;
  int h = hb >> 5, b = hb & 31;
  int tid = threadIdx.x;
  int wave = tid >> 6, lane = tid & 63;
  int l5 = lane >> 5, l31 = lane & 31;
  int quad = lane >> 4, l15 = lane & 15;

  __shared__ u16 Kl[128 * 26];     // [key][26]: 52B rows, 13-bank step (gcd 1)
  __shared__ u16 Vl[16 * 140];     // [k][140]: 280B rows (gcd 2)
  __shared__ u16 Pt[4][64 * 36];   // per wave [q][36]: 72B rows (gcd 2)
  __shared__ u16 KsL[32 * 26];     // station keys
  __shared__ u16 VsL[16 * 44];     // station values transposed

  const u16* Qbase = Qm + ((size_t)(h * 32 + b)) * 16384;
  const u16* QtsB = Qts + ((size_t)(h * 32 + b)) * 16384;
  const u16* Kbase = Kc + ((size_t)(h * 32 + b)) * 16384;
  const u16* Vbase = Vc + ((size_t)(h * 32 + b)) * 16384;
  const u16* KsB = Ks + (size_t)(h * 32 + b) * 512;
  const u16* VsB = Vs + (size_t)(h * 32 + b) * 512;

  // stage station K/V once (visible after first loop barrier)
  if (tid < 64) {
    int key = tid >> 1, half = tid & 1;
    *(uint4*)&KsL[key * 26 + half * 8] = *(const uint4*)(KsB + key * 16 + half * 8);
  } else if (tid < 128) {
    int t = tid - 64;
    int d = t >> 2, kg = t & 3;
    *(uint4*)&VsL[d * 44 + kg * 8] = *(const uint4*)(VsB + d * 32 + kg * 8);
  }

  int qw0 = qc * 256 + wave * 64;
  U4B qf0, qf1;
  qf0.u = *(const uint4*)(Qbase + (size_t)(qw0 + l31) * 16 + l5 * 8);
  qf1.u = *(const uint4*)(Qbase + (size_t)(qw0 + 32 + l31) * 16 + l5 * 8);

  f32x16 zero16;
#pragma unroll
  for (int i = 0; i < 16; ++i) zero16[i] = 0.f;
  U4B ones;
  ones.u = make_uint4(0x3F803F80u, 0x3F803F80u, 0x3F803F80u, 0x3F803F80u);

  f32x4 o[4], la[4];
#pragma unroll
  for (int mt = 0; mt < 4; ++mt)
#pragma unroll
    for (int r = 0; r < 4; ++r) { o[mt][r] = 0.f; la[mt][r] = 0.f; }

#pragma unroll 1
  for (int kb = 0; kb < 8; ++kb) {
    int j0 = kb * 128;
    __syncthreads();
    {
      int key = tid >> 1, half = tid & 1;
      *(uint4*)&Kl[key * 26 + half * 8] =
          *(const uint4*)(Kbase + (size_t)(j0 + key) * 16 + half * 8);
      int d = tid >> 4, kg = tid & 15;
      *(uint4*)&Vl[d * 140 + kg * 8] =
          *(const uint4*)(Vbase + (size_t)d * 1024 + j0 + kg * 8);
    }
    __syncthreads();
#pragma unroll 1
    for (int kt = 0; kt < 4; ++kt) {
      int key0 = kt * 32;
      U4B af;
      af.u = *(const uint4*)&Kl[(key0 + l31) * 26 + l5 * 8];
      f32x16 c0 =
          __builtin_amdgcn_mfma_f32_32x32x16_bf16(af.b, qf0.b, zero16, 0, 0, 0);
      f32x16 c1 =
          __builtin_amdgcn_mfma_f32_32x32x16_bf16(af.b, qf1.b, zero16, 0, 0, 0);
      bool masked = (kb == 0) && (kt == 0);
#pragma unroll
      for (int f = 0; f < 2; ++f) {
        const f32x16& c = f ? c1 : c0;
        int qq = f * 32 + l31;
#pragma unroll
        for (int g = 0; g < 4; ++g) {
          float p0 = __builtin_amdgcn_exp2f(c[4 * g + 0]);
          float p1 = __builtin_amdgcn_exp2f(c[4 * g + 1]);
          float p2 = __builtin_amdgcn_exp2f(c[4 * g + 2]);
          float p3 = __builtin_amdgcn_exp2f(c[4 * g + 3]);
          if (masked) {  // key index of value r is r + 8*g + 4*l5; zero keys<21
            int kb0 = 8 * g + 4 * l5;
            p0 = (kb0 + 0 < NST) ? 0.f : p0;
            p1 = (kb0 + 1 < NST) ? 0.f : p1;
            p2 = (kb0 + 2 < NST) ? 0.f : p2;
            p3 = (kb0 + 3 < NST) ? 0.f : p3;
          }
          uint2 w2 = make_uint2(pkperm(p0, p1), pkperm(p2, p3));
          *(uint2*)&Pt[wave][qq * 36 + 4 * l5 + 8 * g] = w2;
        }
      }
      U4B vf;
      vf.u = *(const uint4*)&Vl[l15 * 140 + key0 + quad * 8];
#pragma unroll
      for (int mt = 0; mt < 4; ++mt) {
        U4B pf;
        pf.u = *(const uint4*)&Pt[wave][(mt * 16 + l15) * 36 + quad * 8];
        o[mt] = __builtin_amdgcn_mfma_f32_16x16x32_bf16(pf.b, vf.b, o[mt], 0, 0, 0);
        la[mt] =
            __builtin_amdgcn_mfma_f32_16x16x32_bf16(pf.b, ones.b, la[mt], 0, 0, 0);
      }
    }
  }

  // ---- fused station pass: Q = Q_ts, keys = K_s/V_s (keys>=21 masked) ----
  f32x4 o2[4], la2[4];
#pragma unroll
  for (int mt = 0; mt < 4; ++mt)
#pragma unroll
    for (int r = 0; r < 4; ++r) { o2[mt][r] = 0.f; la2[mt][r] = 0.f; }
  qf0.u = *(const uint4*)(QtsB + (size_t)(qw0 + l31) * 16 + l5 * 8);
  qf1.u = *(const uint4*)(QtsB + (size_t)(qw0 + 32 + l31) * 16 + l5 * 8);
  {
    U4B af;
    af.u = *(const uint4*)&KsL[l31 * 26 + l5 * 8];
    f32x16 c0 =
        __builtin_amdgcn_mfma_f32_32x32x16_bf16(af.b, qf0.b, zero16, 0, 0, 0);
    f32x16 c1 =
        __builtin_amdgcn_mfma_f32_32x32x16_bf16(af.b, qf1.b, zero16, 0, 0, 0);
#pragma unroll
    for (int f = 0; f < 2; ++f) {
      const f32x16& c = f ? c1 : c0;
      int qq = f * 32 + l31;
#pragma unroll
      for (int g = 0; g < 4; ++g) {
        float p0 = __builtin_amdgcn_exp2f(c[4 * g + 0]);
        float p1 = __builtin_amdgcn_exp2f(c[4 * g + 1]);
        float p2 = __builtin_amdgcn_exp2f(c[4 * g + 2]);
        float p3 = __builtin_amdgcn_exp2f(c[4 * g + 3]);
        int kb0 = 8 * g + 4 * l5;  // zero keys >= 21 (pad rows)
        p0 = (kb0 + 0 >= NST) ? 0.f : p0;
        p1 = (kb0 + 1 >= NST) ? 0.f : p1;
        p2 = (kb0 + 2 >= NST) ? 0.f : p2;
        p3 = (kb0 + 3 >= NST) ? 0.f : p3;
        uint2 w2 = make_uint2(pkperm(p0, p1), pkperm(p2, p3));
        *(uint2*)&Pt[wave][qq * 36 + 4 * l5 + 8 * g] = w2;
      }
    }
    U4B vf;
    vf.u = *(const uint4*)&VsL[l15 * 44 + quad * 8];
#pragma unroll
    for (int mt = 0; mt < 4; ++mt) {
      U4B pf;
      pf.u = *(const uint4*)&Pt[wave][(mt * 16 + l15) * 36 + quad * 8];
      o2[mt] = __builtin_amdgcn_mfma_f32_16x16x32_bf16(pf.b, vf.b, o2[mt], 0, 0, 0);
      la2[mt] =
          __builtin_amdgcn_mfma_f32_16x16x32_bf16(pf.b, ones.b, la2[mt], 0, 0, 0);
    }
  }

  // ---- epilogue: heads bf16 ----
#pragma unroll
  for (int mt = 0; mt < 4; ++mt)
#pragma unroll
    for (int r = 0; r < 4; ++r) {
      int n = qw0 + mt * 16 + quad * 4 + r;
      float val = o[mt][r] * __builtin_amdgcn_rcpf(la[mt][r]);
      if (n >= NST) val += o2[mt][r] * __builtin_amdgcn_rcpf(la2[mt][r]);
      heads[((size_t)b * 1024 + n) * 128 + h * 16 + l15] = bf1(val);
    }
}

// =====================================================================
extern "C" void kernel_launch(void* const* d_in, const int* in_sizes, int n_in,
                              void* d_out, int out_size, void* d_ws,
                              size_t ws_size, hipStream_t stream) {
  (void)in_sizes; (void)n_in; (void)out_size; (void)ws_size;
  const float* q     = (const float*)d_in[0];
  const float* hx    = (const float*)d_in[1];
  const float* W_qts = (const float*)d_in[2];  // W_query_custom   -> Q_ts
  const float* W_qtt = (const float*)d_in[3];  // W_query_custom_1 -> Q_tt
  const float* W_kc  = (const float*)d_in[4];
  const float* W_vc  = (const float*)d_in[5];
  const float* W_qst = (const float*)d_in[6];  // W_query_charge_1 -> Q_st
  const float* W_ks  = (const float*)d_in[7];
  const float* W_vs  = (const float*)d_in[8];
  const float* W_out = (const float*)d_in[9];

  char* ws = (char*)d_ws;
  u16* qhbf  = (u16*)(ws + 0);          // q:8MB + hx:8MB (bf16 casts)
  u16* heads = (u16*)(ws + 0);          // reuse qbf slot (dead after proj4)
  u16* hbf   = (u16*)(ws + 8388608);
  u16* Qm    = (u16*)(ws + 16777216);   // [h][b][1024][16]
  u16* Qts   = (u16*)(ws + 25165824);
  u16* Kc    = (u16*)(ws + 33554432);   // [h][b][1024][16]
  u16* Vc    = (u16*)(ws + 41943040);   // [h][b][16][1024] (transposed)
  u16* Ks    = (u16*)(ws + 50331648);   // [h][b][32][16]
  u16* Vs    = (u16*)(ws + 50593792);   // [h][b][16][32]
  u16* WtAll = (u16*)(ws + 50855936);   // 5 x 128x128 bf16

  hipLaunchKernelGGL(prep, dim3(4648), dim3(256), 0, stream,
                     q, hx, W_qtt, W_qts, W_kc, W_vc, W_out, W_qst, W_ks, W_vs,
                     qhbf, WtAll, Qm, Ks, Vs);
  hipLaunchKernelGGL(proj4, dim3(2048), dim3(256), 0, stream,
                     qhbf, hbf, WtAll, Qm, Qts, Kc, Vc);
  hipLaunchKernelGGL(attn_main, dim3(1024), dim3(256), 0, stream,
                     Qm, Qts, Kc, Vc, Ks, Vs, heads);
  hipLaunchKernelGGL(outproj, dim3(512), dim3(256), 0, stream,
                     heads, WtAll, (float*)d_out);
}